// Round 11
// baseline (119.444 us; speedup 1.0000x reference)
//
#include <hip/hip_runtime.h>

// AllPoleDigitalFilter via overlap-and-discard.
// Numerics (validated R8/R10): frame-aligned start nb=(ci-8)>>1 (warm
// 320..360; ci<8 exact from t=0), exact per-sample gain, per-8-group
// midpoint taps -> absmax 0.0352 (threshold 0.1056).
// R11: cross-round invariant = ~230 SIMD-cyc per wave-sample in BOTH R8
// (1 wave/SIMD, global loads) and R6 (2 waves/SIMD) and it got WORSE with
// LDS (R10) -> memory path exonerated; either hidden issue bloat or
// dependency stalls. Discriminating experiment: interleave TWO independent
// chunk recurrences per thread (ci, ci+800). Stall-bound -> ~2x. 400 waves,
// VGPR budget 512 via waves_per_eu(1,1). I-cache: group loop split as
// half(2) x 5 unrolled groups (40 samples = ring period -> compile-time
// ring indices), hot body ~18KB < 32KB L1I.

typedef float v2f __attribute__((ext_vector_type(2)));

#define BATCH 32
#define N_FRAMES 800
#define D_COEF 25
#define P_FRAME 80
#define T_SAMP 64000
#define LCH 40
#define CHUNKS 1600              // per batch row; 800 pairs per row

__global__
__attribute__((amdgpu_flat_work_group_size(64, 64)))
__attribute__((amdgpu_waves_per_eu(1, 1)))
void lpc_kernel(const float* __restrict__ x,
                const float* __restrict__ a,
                float* __restrict__ out) {
    const int g = blockIdx.x * 64 + threadIdx.x;
    const int b = g / 800;
    const int cpair = g - b * 800;

    const float* xrow = x + (size_t)b * T_SAMP;
    float* orow = out + (size_t)b * T_SAMP;
    const float* arow = a + (size_t)b * (N_FRAMES * D_COEF);

    int s0[2], nb[2], t0[2];
#pragma unroll
    for (int q = 0; q < 2; ++q) {
        int ci = cpair + 800 * q;
        s0[q] = ci * LCH;
        int n = (ci - 8) >> 1; if (n < 0) n = 0;
        nb[q] = n;
        t0[q] = n * P_FRAME;
    }

    float w[2][40];
#pragma unroll
    for (int q = 0; q < 2; ++q)
#pragma unroll
        for (int i = 0; i < 40; ++i) w[q][i] = 0.0f;
#define WQ(q, i) w[q][(i) % 40]

    // x pipeline per chain: xc = current group, xn = next group
    float4 xc0[2], xc1[2], xn0[2], xn1[2];
#pragma unroll
    for (int q = 0; q < 2; ++q) {
        xc0[q] = *(const float4*)(xrow + t0[q]);
        xc1[q] = *(const float4*)(xrow + t0[q] + 4);
        xn0[q] = *(const float4*)(xrow + t0[q] + 8);
        xn1[q] = *(const float4*)(xrow + t0[q] + 12);
    }

    const float inv_p = 1.0f / (float)P_FRAME;

#pragma unroll 1
    for (int f = 0; f < 5; ++f) {
        v2f cp[2][12], dp[2][12];
        float k[2], dk[2];
#pragma unroll
        for (int q = 0; q < 2; ++q) {
            int n = nb[q] + f;
            int n1 = n + 1; if (n1 > N_FRAMES - 1) n1 = N_FRAMES - 1;
            const float* r0 = arow + n * D_COEF;
            const float* r1 = arow + n1 * D_COEF;
            float kk0 = r0[0], kk1 = r1[0];
            dk[q] = (kk1 - kk0) * inv_p;
            k[q] = kk0;
#pragma unroll
            for (int r = 0; r < 12; ++r) {
                float c0x = r0[1 + 2 * r], c0y = r0[2 + 2 * r];
                float c1x = r1[1 + 2 * r], c1y = r1[2 + 2 * r];
                float ddx = (c1x - c0x) * inv_p;
                float ddy = (c1y - c0y) * inv_p;
                cp[q][r].x = fmaf(ddx, 3.5f, c0x);
                cp[q][r].y = fmaf(ddy, 3.5f, c0y);
                dp[q][r].x = 8.0f * ddx;
                dp[q][r].y = 8.0f * ddy;
            }
        }
#define CT(q, m) ((m) & 1 ? cp[q][((m) - 1) >> 1].x : cp[q][((m) - 2) >> 1].y)

#pragma unroll 1
        for (int half = 0; half < 2; ++half) {
#pragma unroll
            for (int e = 0; e < 5; ++e) {
                const int gg = half * 5 + e;          // runtime half, ct e
                // prefetch x two groups ahead, per chain
                float4 xf0[2], xf1[2];
#pragma unroll
                for (int q = 0; q < 2; ++q) {
                    int tg = t0[q] + f * P_FRAME + gg * 8;
                    int tp = tg + 16; if (tp > T_SAMP - 8) tp = T_SAMP - 8;
                    xf0[q] = *(const float4*)(xrow + tp);
                    xf1[q] = *(const float4*)(xrow + tp + 4);
                }

#pragma unroll
                for (int j = 0; j < 8; ++j) {
                    const int P = 24 + 8 * e + j;     // ring pos mod 40 (half*40 == 0)
#pragma unroll
                    for (int q = 0; q < 2; ++q) {
                        float xv = (j == 0) ? xc0[q].x : (j == 1) ? xc0[q].y
                                 : (j == 2) ? xc0[q].z : (j == 3) ? xc0[q].w
                                 : (j == 4) ? xc1[q].x : (j == 5) ? xc1[q].y
                                 : (j == 6) ? xc1[q].z : xc1[q].w;
                        float ev = k[q] * xv;
                        float ch0 = fmaf(-CT(q, 3), WQ(q, P - 3), ev);
                        float ch1 = -CT(q, 4) * WQ(q, P - 4);
                        float ch2 = -CT(q, 5) * WQ(q, P - 5);
                        float ch3 = -CT(q, 6) * WQ(q, P - 6);
#pragma unroll
                        for (int m = 7; m <= 24; ++m) {
                            if ((m & 3) == 3)      ch0 = fmaf(-CT(q, m), WQ(q, P - m), ch0);
                            else if ((m & 3) == 0) ch1 = fmaf(-CT(q, m), WQ(q, P - m), ch1);
                            else if ((m & 3) == 1) ch2 = fmaf(-CT(q, m), WQ(q, P - m), ch2);
                            else                   ch3 = fmaf(-CT(q, m), WQ(q, P - m), ch3);
                        }
                        float partial = (ch0 + ch1) + (ch2 + ch3);
                        float u = fmaf(-CT(q, 2), WQ(q, P - 2), partial);
                        float y = fmaf(-CT(q, 1), WQ(q, P - 1), u);
                        WQ(q, P) = y;
                        k[q] += dk[q];
                    }
                }

#pragma unroll
                for (int q = 0; q < 2; ++q) {
                    int tg = t0[q] + f * P_FRAME + gg * 8;
                    if ((unsigned)(tg - s0[q]) < 40u) {   // multiples of 8
                        const int Q = 24 + 8 * e;
                        *(float4*)(orow + tg)     = make_float4(WQ(q, Q + 0), WQ(q, Q + 1), WQ(q, Q + 2), WQ(q, Q + 3));
                        *(float4*)(orow + tg + 4) = make_float4(WQ(q, Q + 4), WQ(q, Q + 5), WQ(q, Q + 6), WQ(q, Q + 7));
                    }
                    if (gg < 9) {
#pragma unroll
                        for (int r = 0; r < 12; ++r) cp[q][r] += dp[q][r];
                    }
                    xc0[q] = xn0[q]; xc1[q] = xn1[q];   // rotate at group END
                    xn0[q] = xf0[q]; xn1[q] = xf1[q];
                }
            }
        }
#undef CT
    }
#undef WQ
}

extern "C" void kernel_launch(void* const* d_in, const int* in_sizes, int n_in,
                              void* d_out, int out_size, void* d_ws, size_t ws_size,
                              hipStream_t stream) {
    const float* x = (const float*)d_in[0];
    const float* a = (const float*)d_in[1];
    float* out = (float*)d_out;

    dim3 block(64);
    dim3 grid(BATCH * 800 / 64);         // 400 blocks, 1 wave each
    hipLaunchKernelGGL(lpc_kernel, grid, block, 0, stream, x, a, out);
}

// Round 13
// 82.367 us; speedup vs baseline: 1.4501x; 1.4501x over previous
//
#include <hip/hip_runtime.h>

// AllPoleDigitalFilter via overlap-and-discard.
// Numerics (validated R8/R10/R11): frame-aligned start nb=(ci-8)>>1 (warm
// 320..360; ci<8 exact from t=0), exact per-sample gain, per-8-group
// midpoint taps -> absmax 0.0352 (threshold 0.1056).
// R12 theory (unrefuted): issue-bound ~131 SIMD-cyc/sample (R6 & R11 agree
// to 1%), ~2x hand count -> halve instr count with v_pk_fma_f32 over a
// DUAL-ALIGNED v2f history ring: wA[i]={y[2i],y[2i+1]} serves even samples,
// wB[i]={y[2i+1],y[2i+2]} serves odd samples -> pk operands never need
// pair-building movs (cost: 1 mirror mov/sample). Packed negated coeffs
// {-a_{4+2r}, -a_{3+2r}} are parity-invariant. Taps 1,2 scalar (1-FMA
// inter-sample critical path). R12 crashed (runtime abort, cause not
// identified by audit); R13 hardens: constexpr index helpers with +80 bias
// before %40, element-wise vector init, explicit component stores.

typedef float v2f __attribute__((ext_vector_type(2)));

#define BATCH 32
#define N_FRAMES 800
#define D_COEF 25
#define P_FRAME 80
#define T_SAMP 64000
#define LCH 40
#define CHUNKS 1600              // per batch row

// ring slot helpers (all args non-negative; +80 bias removes any doubt)
__device__ __forceinline__ constexpr int slotA(int s)  { return ((s + 80) % 40) / 2; }       // even s: wA[slotA].x=y[s]; odd s uses slotAy
__device__ __forceinline__ constexpr int slotAy(int s) { return ((s + 80 - 1) % 40) / 2; }   // odd s: wA[slotAy].y=y[s]
__device__ __forceinline__ constexpr int slotBx(int s) { return ((s + 80 - 1) % 40) / 2; }   // odd s: wB[slotBx].x=y[s]
__device__ __forceinline__ constexpr int slotBy(int s) { return ((s + 80 - 2) % 40) / 2; }   // even s: wB[slotBy].y=y[s]

__global__
__attribute__((amdgpu_flat_work_group_size(64, 64)))
__attribute__((amdgpu_waves_per_eu(1, 1)))
void lpc_kernel(const float* __restrict__ x,
                const float* __restrict__ a,
                float* __restrict__ out) {
    const int g = blockIdx.x * 64 + threadIdx.x;
    const int b = g / CHUNKS;
    const int ci = g - b * CHUNKS;
    const int s0 = ci * LCH;
    int nb = (ci - 8) >> 1; if (nb < 0) nb = 0;
    const int t0 = nb * P_FRAME;

    const float* xrow = x + (size_t)b * T_SAMP;
    float* orow = out + (size_t)b * T_SAMP;
    const float* arow = a + (size_t)b * (N_FRAMES * D_COEF);

    v2f wA[20], wB[20];
#pragma unroll
    for (int i = 0; i < 20; ++i) {
        wA[i].x = 0.0f; wA[i].y = 0.0f;
        wB[i].x = 0.0f; wB[i].y = 0.0f;
    }

    float4 xc0 = *(const float4*)(xrow + t0);
    float4 xc1 = *(const float4*)(xrow + t0 + 4);
    float4 xn0 = *(const float4*)(xrow + t0 + 8);
    float4 xn1 = *(const float4*)(xrow + t0 + 12);

    const float inv_p = 1.0f / (float)P_FRAME;

#pragma unroll 1
    for (int f = 0; f < 5; ++f) {
        const int n = nb + f;
        const int n1 = (n + 1 < N_FRAMES) ? n + 1 : N_FRAMES - 1;
        const float* r0 = arow + n * D_COEF;
        const float* r1 = arow + n1 * D_COEF;

        float g0 = r0[0];
        float dk = (r1[0] - g0) * inv_p;
        float k = g0;

        float nc1, nc2, dn1, dn2;
        {
            float c1 = r0[1], c2 = r0[2];
            float d1 = (r1[1] - c1) * inv_p;
            float d2 = (r1[2] - c2) * inv_p;
            nc1 = -fmaf(d1, 3.5f, c1);  dn1 = -8.0f * d1;
            nc2 = -fmaf(d2, 3.5f, c2);  dn2 = -8.0f * d2;
        }
        v2f cp[11], d8[11];
#pragma unroll
        for (int r = 0; r < 11; ++r) {
            float cLo = r0[4 + 2 * r], cHi = r0[3 + 2 * r];
            float dLo = (r1[4 + 2 * r] - cLo) * inv_p;
            float dHi = (r1[3 + 2 * r] - cHi) * inv_p;
            cp[r].x = -fmaf(dLo, 3.5f, cLo);
            cp[r].y = -fmaf(dHi, 3.5f, cHi);
            d8[r].x = -8.0f * dLo;
            d8[r].y = -8.0f * dHi;
        }

        const int tf = t0 + f * P_FRAME;

#pragma unroll
        for (int gg = 0; gg < 10; ++gg) {
            const int tg = tf + gg * 8;
            int tp = tg + 16; if (tp > T_SAMP - 8) tp = T_SAMP - 8;
            float4 xf0 = *(const float4*)(xrow + tp);
            float4 xf1 = *(const float4*)(xrow + tp + 4);

#pragma unroll
            for (int j = 0; j < 8; ++j) {
                const int P = 24 + gg * 8 + j;        // compile-time ring pos
                float xv = (j == 0) ? xc0.x : (j == 1) ? xc0.y
                         : (j == 2) ? xc0.z : (j == 3) ? xc0.w
                         : (j == 4) ? xc1.x : (j == 5) ? xc1.y
                         : (j == 6) ? xc1.z : xc1.w;
                float e = k * xv;

                // taps 3..24: 11 pk ops, 3 chains; pair r covers lags 3+2r,4+2r
                v2f A, B, C;
#pragma unroll
                for (int r = 0; r < 11; ++r) {
                    // pair {y[P-4-2r], y[P-3-2r]}: even P from wA, odd P from wB
                    v2f pr = (P & 1) ? wB[slotBx(P - 3 - 2 * r)]
                                     : wA[slotA(P - 4 - 2 * r)];
                    if (r == 0)          A = cp[r] * pr;
                    else if (r == 1)     B = cp[r] * pr;
                    else if (r == 2)     C = cp[r] * pr;
                    else if (r % 3 == 0) A += cp[r] * pr;
                    else if (r % 3 == 1) B += cp[r] * pr;
                    else                 C += cp[r] * pr;
                }
                v2f S = (A + B) + C;
                float t1 = e + (S.x + S.y);
                float ym1 = (P & 1) ? wA[slotA(P - 1)].x  : wA[slotAy(P - 1)].y;  // y[P-1]
                float ym2 = (P & 1) ? wA[slotAy(P - 2)].y : wA[slotA(P - 2)].x;   // y[P-2]
                float u = fmaf(nc2, ym2, t1);
                float y = fmaf(nc1, ym1, u);

                // mirror write into both rings
                if (P & 1) {
                    wA[slotAy(P)].y = y;
                    wB[slotBx(P)].x = y;
                } else {
                    wA[slotA(P)].x = y;
                    wB[slotBy(P)].y = y;
                }
                k += dk;
            }

            if ((unsigned)(tg - s0) < 40u) {          // tg, s0 multiples of 8
                const int Q = 24 + gg * 8;            // Q even -> pairs from wA
                *(float4*)(orow + tg)     = make_float4(wA[slotA(Q + 0)].x, wA[slotA(Q + 0)].y,
                                                        wA[slotA(Q + 2)].x, wA[slotA(Q + 2)].y);
                *(float4*)(orow + tg + 4) = make_float4(wA[slotA(Q + 4)].x, wA[slotA(Q + 4)].y,
                                                        wA[slotA(Q + 6)].x, wA[slotA(Q + 6)].y);
            }
            if (gg < 9) {
                nc1 += dn1; nc2 += dn2;
#pragma unroll
                for (int r = 0; r < 11; ++r) cp[r] += d8[r];   // v_pk_add_f32
            }
            xc0 = xn0; xc1 = xn1;                     // rotate at group END
            xn0 = xf0; xn1 = xf1;
        }
    }
}

extern "C" void kernel_launch(void* const* d_in, const int* in_sizes, int n_in,
                              void* d_out, int out_size, void* d_ws, size_t ws_size,
                              hipStream_t stream) {
    const float* x = (const float*)d_in[0];
    const float* a = (const float*)d_in[1];
    float* out = (float*)d_out;

    dim3 block(64);
    dim3 grid(BATCH * CHUNKS / 64);      // 800 one-wave blocks
    hipLaunchKernelGGL(lpc_kernel, grid, block, 0, stream, x, a, out);
}